// Round 20
// baseline (54.090 us; speedup 1.0000x reference)
//
#include <hip/hip_runtime.h>
#include <hip/hip_bf16.h>
#include <hip/hip_fp8.h>

#define B_ROWS 8192
#define E_DIM  1024
#define MARGIN 0.2f
#define BK 64                 // fp8 elements per K-step (2 ktiles of 32)
#define NSTEPS (E_DIM / BK)   // 16
#define WSCALE 16.0f          // W scaled into e4m3 sweet spot; undone in epilogue

typedef float f32x4 __attribute__((ext_vector_type(4)));

__device__ __forceinline__ void gload_lds16(const void* g, void* l) {
    __builtin_amdgcn_global_load_lds(
        (__attribute__((address_space(1))) void*)(g),
        (__attribute__((address_space(3))) void*)(l),
        16, 0, 0);
}

#define GATE(N) do { asm volatile("s_waitcnt vmcnt(" #N ")" ::: "memory"); \
                     __builtin_amdgcn_sched_barrier(0); } while (0)
#define RBAR()  do { __builtin_amdgcn_s_barrier(); \
                     __builtin_amdgcn_sched_barrier(0); } while (0)
#define LGKM0() do { asm volatile("s_waitcnt lgkmcnt(0)" ::: "memory"); \
                     __builtin_amdgcn_sched_barrier(0); } while (0)
#define LOADF(dst, addr) \
    asm volatile("global_load_dword %0, %1, off" : "=v"(dst) : "v"(addr))

__device__ __forceinline__ unsigned char to_fp8(float x) {
    return __hip_fp8_e4m3(x).__x;
}

// Fragment-packed layouts (unit = [panel64][ktile32], 2 KiB each):
//   unit byte (mi*512 + lane*8 + j) = value[row = panel*64 + mi*16 + (lane&15)]
//                                          [k   = ktile*32 + (lane>>4)*8 + j]
// c8p: 128 panels x 32 ktiles (8 MiB). wtp: 16 panels x 32 ktiles (1 MiB),
// value = 16*W[k][n] (transposed on the fly).
// blocks [0,4096): c-pack; [4096,4608): W-pack; [4608,4640): zero delta.
__global__ __launch_bounds__(256)
void prep_combo(const float* __restrict__ m, const float* __restrict__ trm,
                unsigned char* __restrict__ c8p,
                const float* __restrict__ W, unsigned char* __restrict__ wtp,
                float* __restrict__ delta) {
    const int tid = threadIdx.x;
    const int mi  = tid >> 6;
    const int l   = tid & 63;
    const int lr  = l & 15;
    const int hi  = l >> 4;
    if (blockIdx.x < 4096) {
        const int unit  = blockIdx.x;
        const int panel = unit >> 5;
        const int kt    = unit & 31;
        const size_t g  = (size_t)(panel * 64 + mi * 16 + lr) * E_DIM + kt * 32 + hi * 8;
        float4 m0 = *(const float4*)(m + g);
        float4 m1 = *(const float4*)(m + g + 4);
        float4 t0 = *(const float4*)(trm + g);
        float4 t1 = *(const float4*)(trm + g + 4);
        union { unsigned char b[8]; unsigned long long u; } r;
        r.b[0] = to_fp8(0.4f*m0.x + 0.6f*t0.x);
        r.b[1] = to_fp8(0.4f*m0.y + 0.6f*t0.y);
        r.b[2] = to_fp8(0.4f*m0.z + 0.6f*t0.z);
        r.b[3] = to_fp8(0.4f*m0.w + 0.6f*t0.w);
        r.b[4] = to_fp8(0.4f*m1.x + 0.6f*t1.x);
        r.b[5] = to_fp8(0.4f*m1.y + 0.6f*t1.y);
        r.b[6] = to_fp8(0.4f*m1.z + 0.6f*t1.z);
        r.b[7] = to_fp8(0.4f*m1.w + 0.6f*t1.w);
        *(unsigned long long*)(c8p + (size_t)unit * 2048 + mi * 512 + l * 8) = r.u;
    } else if (blockIdx.x < 4608) {
        const int unit = blockIdx.x - 4096;
        const int np   = unit >> 5;
        const int kt   = unit & 31;
        const int n    = np * 64 + mi * 16 + lr;
        const int k0   = kt * 32 + hi * 8;
        union { unsigned char b[8]; unsigned long long u; } r;
#pragma unroll
        for (int j = 0; j < 8; ++j)
            r.b[j] = to_fp8(W[(size_t)(k0 + j) * E_DIM + n] * WSCALE);
        *(unsigned long long*)(wtp + (size_t)unit * 2048 + mi * 512 + l * 8) = r.u;
    } else {
        delta[(blockIdx.x - 4608) * 256 + threadIdx.x] = 0.f;
    }
}

// R18 packed GEMM + IN-LOOP dA STREAMING: the epilogue's 128 strided loads
// of Ais/Aem (independent of the K-loop) are issued as asm-pinned batches
// of 8 per iteration (4 Ais + 4 Aem), absorbed into the K-loop's idle BW
// instead of bursting post-loop. vmcnt gates extended: steady GATE(12)
// (worst-case-safe vs any intra-window reorder of stage vs dA), tail 8 -> 0.
// Batch t certified at iter t+2's gate -> diff computed there (ring-of-2
// tmp regs, 16 + 64 diff f32). Full 16x unroll: all indices static (#20);
// sched_barrier(0) after every waitcnt (#18). Frag reads lane-linear
// (0 conflicts, R18-verified). Epilogue: pure-register dot + reduce.
__global__ __launch_bounds__(256)
void gemm_dot(const unsigned char* __restrict__ c8p, const unsigned char* __restrict__ wtp,
              const float* __restrict__ Ais, const float* __restrict__ Aem,
              float* __restrict__ delta) {
    __shared__ char smem[49152];   // slot s: A at s*16384, B at s*16384+8192

    const int tid  = threadIdx.x;
    const int lane = tid & 63;
    const int lr   = lane & 15;
    const int hi   = lane >> 4;
    const int wave = tid >> 6;
    const int wr   = wave >> 1, wc = wave & 1;

    // XCD swizzle: xcd owns 8 row-panels x 8 colb.
    const int bid = blockIdx.x;
    const int xcd = bid & 7;
    const int q   = bid >> 3;            // 0..63
    const int rb  = (xcd * 8 + (q >> 3)) * 128;
    const int cb  = (q & 7) * 128;
    const int ap0 = rb >> 6;
    const int bp0 = cb >> 6;

    const int rowbase = rb + wr * 64 + hi * 4;
    const int colbase = cb + wc * 64 + lr;
    const unsigned long long isb = (unsigned long long)(uintptr_t)Ais;
    const unsigned long long emb = (unsigned long long)(uintptr_t)Aem;

    auto stage = [&](int slot, int t) {
#pragma unroll
        for (int j = 0; j < 2; ++j) {
            const int off = j * 4096 + tid * 16;
            const int u   = off >> 11;
            const int w   = off & 2047;
            const size_t gA = ((size_t)(ap0 + (u >> 1)) * 32 + (2 * t + (u & 1))) * 2048 + w;
            const size_t gB = ((size_t)(bp0 + (u >> 1)) * 32 + (2 * t + (u & 1))) * 2048 + w;
            gload_lds16(c8p + gA, smem + slot * 16384 + off);
            gload_lds16(wtp + gB, smem + slot * 16384 + 8192 + off);
        }
    };

    f32x4 acc[4][4] = {};
    float diff[64];
    float tis[8], tem[8];

    stage(0, 0);
    stage(1, 1);

#pragma unroll
    for (int t = 0; t < NSTEPS; ++t) {
        // gates (worst-case-reorder-safe): certify stage(t) and dA(t-2)
        if (t == 0)                 GATE(4);
        else if (t == NSTEPS - 1)   GATE(8);
        else                        GATE(12);
        RBAR();

        // consume certified dA batch t-2 (tmp ring slot t&1)
        if (t >= 2) {
#pragma unroll
            for (int r = 0; r < 4; ++r)
                diff[(t - 2) * 4 + r] = tis[(t & 1) * 4 + r] - tem[(t & 1) * 4 + r];
        }

        // frag reads: lane-linear, conflict-free
        const char* Ab = smem + (t % 3) * 16384;
        const char* Bb = Ab + 8192;
        long a[4][2], b[4][2];
#pragma unroll
        for (int kk = 0; kk < 2; ++kk) {
            const int au = (wr * 2 + kk) * 2048 + lane * 8;
            const int bu = (wc * 2 + kk) * 2048 + lane * 8;
#pragma unroll
            for (int mi = 0; mi < 4; ++mi) a[mi][kk] = *(const long*)(Ab + au + mi * 512);
#pragma unroll
            for (int ni = 0; ni < 4; ++ni) b[ni][kk] = *(const long*)(Bb + bu + ni * 512);
        }
        LGKM0();

        if (t + 2 < NSTEPS) stage((t + 2) % 3, t + 2);

        // issue dA batch t: positions q = 4t..4t+3 (asm-pinned, unsinkable)
        {
#pragma unroll
            for (int r = 0; r < 4; ++r) {
                const int qq = t * 4 + r;
                const int mi = qq >> 4, jj = (qq >> 2) & 3, ni = qq & 3;
                const unsigned long long off =
                    ((unsigned long long)(rowbase + mi * 16 + jj) * E_DIM
                     + colbase + ni * 16) * 4ull;
                LOADF(tis[(t & 1) * 4 + r], isb + off);
                LOADF(tem[(t & 1) * 4 + r], emb + off);
            }
        }

        __builtin_amdgcn_s_setprio(1);
#pragma unroll
        for (int kk = 0; kk < 2; ++kk)
#pragma unroll
            for (int mi = 0; mi < 4; ++mi)
#pragma unroll
                for (int ni = 0; ni < 4; ++ni)
                    acc[mi][ni] = __builtin_amdgcn_mfma_f32_16x16x32_fp8_fp8(
                        a[mi][kk], b[ni][kk], acc[mi][ni], 0, 0, 0);
        __builtin_amdgcn_s_setprio(0);
    }

    // drain last two dA batches (14, 15)
    GATE(0);
#pragma unroll
    for (int b2 = NSTEPS - 2; b2 < NSTEPS; ++b2)
#pragma unroll
        for (int r = 0; r < 4; ++r)
            diff[b2 * 4 + r] = tis[(b2 & 1) * 4 + r] - tem[(b2 & 1) * 4 + r];

    // epilogue: pure-register dot + 16-lane reduce + atomicAdd
    // C/D layout (16x16x32): col = lane&15, row = (lane>>4)*4 + reg
#pragma unroll
    for (int mi = 0; mi < 4; ++mi) {
#pragma unroll
        for (int jj = 0; jj < 4; ++jj) {
            const int r = rowbase + mi * 16 + jj;
            float v = 0.f;
#pragma unroll
            for (int ni = 0; ni < 4; ++ni)
                v += acc[mi][ni][jj] * diff[mi * 16 + jj * 4 + ni];
            v += __shfl_xor(v, 1);
            v += __shfl_xor(v, 2);
            v += __shfl_xor(v, 4);
            v += __shfl_xor(v, 8);
            if (lr == 0) atomicAdd(&delta[r], v * (1.0f / WSCALE));
        }
    }
}

__global__ void hinge_sum(const float* __restrict__ delta, float* __restrict__ out) {
    float s = 0.f;
    for (int i = threadIdx.x; i < B_ROWS; i += 256)
        s += fmaxf(MARGIN + delta[i], 0.f);
#pragma unroll
    for (int off = 32; off > 0; off >>= 1) s += __shfl_down(s, off);
    __shared__ float wsum[4];
    int lane = threadIdx.x & 63, w = threadIdx.x >> 6;
    if (lane == 0) wsum[w] = s;
    __syncthreads();
    if (threadIdx.x == 0) out[0] = wsum[0] + wsum[1] + wsum[2] + wsum[3];
}

extern "C" void kernel_launch(void* const* d_in, const int* in_sizes, int n_in,
                              void* d_out, int out_size, void* d_ws, size_t ws_size,
                              hipStream_t stream) {
    const float* A_is = (const float*)d_in[0];
    const float* A_em = (const float*)d_in[1];
    const float* m    = (const float*)d_in[2];
    const float* tr_m = (const float*)d_in[3];
    const float* W    = (const float*)d_in[4];
    // d_in[5] = b : cancels in diag_is - diag_em, unused.
    float* out = (float*)d_out;

    char* ws = (char*)d_ws;
    unsigned char* c8p = (unsigned char*)ws;                             // 8 MiB
    unsigned char* wtp = (unsigned char*)(ws + (size_t)8 * 1024 * 1024); // 1 MiB
    float*         delta = (float*)(ws + (size_t)9 * 1024 * 1024);       // 32 KiB

    prep_combo<<<4640, 256, 0, stream>>>(m, tr_m, c8p, W, wtp, delta);
    gemm_dot<<<512, 256, 0, stream>>>(c8p, wtp, A_is, A_em, delta);
    hinge_sum<<<1, 256, 0, stream>>>(delta, out);
}

// Round 21
// 50.352 us; speedup vs baseline: 1.0742x; 1.0742x over previous
//
#include <hip/hip_runtime.h>
#include <hip/hip_bf16.h>
#include <hip/hip_fp8.h>

#define B_ROWS 8192
#define E_DIM  1024
#define MARGIN 0.2f
#define BK 64                 // fp8 elements per K-step (2 ktiles of 32)
#define NSTEPS (E_DIM / BK)   // 16
#define WSCALE 16.0f          // W scaled into e4m3 sweet spot; undone in epilogue

typedef float f32x4 __attribute__((ext_vector_type(4)));

__device__ __forceinline__ void gload_lds16(const void* g, void* l) {
    __builtin_amdgcn_global_load_lds(
        (__attribute__((address_space(1))) void*)(g),
        (__attribute__((address_space(3))) void*)(l),
        16, 0, 0);
}

#define GATE(N) do { asm volatile("s_waitcnt vmcnt(" #N ")" ::: "memory"); \
                     __builtin_amdgcn_sched_barrier(0); } while (0)
#define RBAR()  do { __builtin_amdgcn_s_barrier(); \
                     __builtin_amdgcn_sched_barrier(0); } while (0)
#define LGKM0() do { asm volatile("s_waitcnt lgkmcnt(0)" ::: "memory"); \
                     __builtin_amdgcn_sched_barrier(0); } while (0)

__device__ __forceinline__ unsigned char to_fp8(float x) {
    return __hip_fp8_e4m3(x).__x;
}

// Fragment-packed layouts (unit = [panel64][ktile32], 2 KiB each):
//   unit byte (mi*512 + lane*8 + j) = value[row = panel*64 + mi*16 + (lane&15)]
//                                          [k   = ktile*32 + (lane>>4)*8 + j]
// c8p: 128 panels x 32 ktiles (8 MiB). wtp: 16 panels x 32 ktiles (1 MiB),
// value = 16*W[k][n] (transposed on the fly).
// blocks [0,4096): c-pack; [4096,4608): W-pack; [4608,4640): zero delta.
__global__ __launch_bounds__(256)
void prep_combo(const float* __restrict__ m, const float* __restrict__ trm,
                unsigned char* __restrict__ c8p,
                const float* __restrict__ W, unsigned char* __restrict__ wtp,
                float* __restrict__ delta) {
    const int tid = threadIdx.x;
    const int mi  = tid >> 6;
    const int l   = tid & 63;
    const int lr  = l & 15;
    const int hi  = l >> 4;
    if (blockIdx.x < 4096) {
        const int unit  = blockIdx.x;
        const int panel = unit >> 5;
        const int kt    = unit & 31;
        const size_t g  = (size_t)(panel * 64 + mi * 16 + lr) * E_DIM + kt * 32 + hi * 8;
        float4 m0 = *(const float4*)(m + g);
        float4 m1 = *(const float4*)(m + g + 4);
        float4 t0 = *(const float4*)(trm + g);
        float4 t1 = *(const float4*)(trm + g + 4);
        union { unsigned char b[8]; unsigned long long u; } r;
        r.b[0] = to_fp8(0.4f*m0.x + 0.6f*t0.x);
        r.b[1] = to_fp8(0.4f*m0.y + 0.6f*t0.y);
        r.b[2] = to_fp8(0.4f*m0.z + 0.6f*t0.z);
        r.b[3] = to_fp8(0.4f*m0.w + 0.6f*t0.w);
        r.b[4] = to_fp8(0.4f*m1.x + 0.6f*t1.x);
        r.b[5] = to_fp8(0.4f*m1.y + 0.6f*t1.y);
        r.b[6] = to_fp8(0.4f*m1.z + 0.6f*t1.z);
        r.b[7] = to_fp8(0.4f*m1.w + 0.6f*t1.w);
        *(unsigned long long*)(c8p + (size_t)unit * 2048 + mi * 512 + l * 8) = r.u;
    } else if (blockIdx.x < 4608) {
        const int unit = blockIdx.x - 4096;
        const int np   = unit >> 5;
        const int kt   = unit & 31;
        const int n    = np * 64 + mi * 16 + lr;
        const int k0   = kt * 32 + hi * 8;
        union { unsigned char b[8]; unsigned long long u; } r;
#pragma unroll
        for (int j = 0; j < 8; ++j)
            r.b[j] = to_fp8(W[(size_t)(k0 + j) * E_DIM + n] * WSCALE);
        *(unsigned long long*)(wtp + (size_t)unit * 2048 + mi * 512 + l * 8) = r.u;
    } else {
        delta[(blockIdx.x - 4608) * 256 + threadIdx.x] = 0.f;
    }
}

// GENERATION-OVERLAP GEMM: tile 128x64, grid 1024 (64 panels x 16 colb --
// every block owns distinct (rows,cols): NO dA duplication), LDS 36 KiB ->
// 4 blocks/CU resident (16 waves/CU). Block X's epilogue burst (HBM pipe)
// hides under blocks Y/Z/W's K-loops (LDS/MFMA pipes). All components
// verified: packed conflict-free layout (R18), ring-of-3 + counted GATE(3)
// (3 gload_lds/thread/step) + one raw barrier (R8/R15/R18), fp8 math +
// epilogue (R17/R18). 4 waves each own 64x32 output (acc[4][2]).
__global__ __launch_bounds__(256)
void gemm_dot(const unsigned char* __restrict__ c8p, const unsigned char* __restrict__ wtp,
              const float* __restrict__ Ais, const float* __restrict__ Aem,
              float* __restrict__ delta) {
    __shared__ char smem[36864];   // slot s at s*12288: A 8 KiB | B 4 KiB

    const int tid  = threadIdx.x;
    const int lane = tid & 63;
    const int lr   = lane & 15;
    const int hi   = lane >> 4;
    const int wave = tid >> 6;
    const int wr   = wave >> 1;          // 0..1 : 64-row half
    const int wc   = wave & 1;           // 0..1 : 32-col half

    // XCD swizzle: xcd owns 8 row-panels x 16 colb; per-XCD reuse set =
    // 8 c8-panels (1 MiB) + wtp (1 MiB) ~ L2-resident.
    const int bid = blockIdx.x;
    const int xcd = bid & 7;
    const int q   = bid >> 3;            // 0..127
    const int rb  = (xcd * 8 + (q >> 4)) * 128;
    const int cb  = (q & 15) * 64;
    const int ap0 = rb >> 6;             // first A panel (of 2)
    const int bp0 = cb >> 6;             // B panel (1)

    // stage one K-step (12 KiB: A 4 units + B 2 units), identity copy;
    // 3 gload_lds per thread.
    auto stage = [&](int slot, int t) {
#pragma unroll
        for (int j = 0; j < 2; ++j) {
            const int off = j * 4096 + tid * 16;   // 0..8191 (A region)
            const int u   = off >> 11;             // 0..3
            const int w   = off & 2047;
            const size_t gA = ((size_t)(ap0 + (u >> 1)) * 32 + (2 * t + (u & 1))) * 2048 + w;
            gload_lds16(c8p + gA, smem + slot * 12288 + off);
        }
        {
            const int off2 = tid * 16;             // 0..4095 (B region)
            const int u2   = off2 >> 11;           // 0..1
            const int w2   = off2 & 2047;
            const size_t gB = ((size_t)bp0 * 32 + (2 * t + u2)) * 2048 + w2;
            gload_lds16(wtp + gB, smem + slot * 12288 + 8192 + off2);
        }
    };

    f32x4 acc[4][2] = {};

    stage(0, 0);
    stage(1, 1);

    int s0 = 0, s1 = 1, s2 = 2;
    for (int t = 0; t < NSTEPS; ++t) {
        if (t + 1 < NSTEPS) GATE(3); else GATE(0);   // certify tile t
        RBAR();

        // frag reads: lane-linear (base + lane*8), conflict-free
        const char* Ab = smem + s0 * 12288;
        const char* Bb = Ab + 8192;
        long a[4][2], b[2][2];
#pragma unroll
        for (int kk = 0; kk < 2; ++kk) {
            const int au = (wr * 2 + kk) * 2048 + lane * 8;   // A panel wr, ktile kk
            const int bu = kk * 2048 + wc * 1024 + lane * 8;  // B ktile kk, col-half wc
#pragma unroll
            for (int mi = 0; mi < 4; ++mi) a[mi][kk] = *(const long*)(Ab + au + mi * 512);
#pragma unroll
            for (int ni = 0; ni < 2; ++ni) b[ni][kk] = *(const long*)(Bb + bu + ni * 512);
        }
        LGKM0();

        if (t + 2 < NSTEPS) stage(s2, t + 2);

        __builtin_amdgcn_s_setprio(1);
#pragma unroll
        for (int kk = 0; kk < 2; ++kk)
#pragma unroll
            for (int mi = 0; mi < 4; ++mi)
#pragma unroll
                for (int ni = 0; ni < 2; ++ni)
                    acc[mi][ni] = __builtin_amdgcn_mfma_f32_16x16x32_fp8_fp8(
                        a[mi][kk], b[ni][kk], acc[mi][ni], 0, 0, 0);
        __builtin_amdgcn_s_setprio(0);

        int tmp = s0; s0 = s1; s1 = s2; s2 = tmp;
    }

    // epilogue (R15/R18-verified form): delta[r] += (1/WSCALE)*sum_col u*dA
    // C/D layout (16x16x32): col = lane&15, row = (lane>>4)*4 + reg
    const int colbase = cb + wc * 32 + lr;
    const int rowbase = rb + wr * 64 + hi * 4;
#pragma unroll
    for (int mi = 0; mi < 4; ++mi) {
#pragma unroll
        for (int jj = 0; jj < 4; ++jj) {
            const int r = rowbase + mi * 16 + jj;
            float v = 0.f;
#pragma unroll
            for (int ni = 0; ni < 2; ++ni) {
                const size_t idx = (size_t)r * E_DIM + colbase + ni * 16;
                v += acc[mi][ni][jj] * (Ais[idx] - Aem[idx]);
            }
            v += __shfl_xor(v, 1);
            v += __shfl_xor(v, 2);
            v += __shfl_xor(v, 4);
            v += __shfl_xor(v, 8);
            if (lr == 0) atomicAdd(&delta[r], v * (1.0f / WSCALE));
        }
    }
}

__global__ void hinge_sum(const float* __restrict__ delta, float* __restrict__ out) {
    float s = 0.f;
    for (int i = threadIdx.x; i < B_ROWS; i += 256)
        s += fmaxf(MARGIN + delta[i], 0.f);
#pragma unroll
    for (int off = 32; off > 0; off >>= 1) s += __shfl_down(s, off);
    __shared__ float wsum[4];
    int lane = threadIdx.x & 63, w = threadIdx.x >> 6;
    if (lane == 0) wsum[w] = s;
    __syncthreads();
    if (threadIdx.x == 0) out[0] = wsum[0] + wsum[1] + wsum[2] + wsum[3];
}

extern "C" void kernel_launch(void* const* d_in, const int* in_sizes, int n_in,
                              void* d_out, int out_size, void* d_ws, size_t ws_size,
                              hipStream_t stream) {
    const float* A_is = (const float*)d_in[0];
    const float* A_em = (const float*)d_in[1];
    const float* m    = (const float*)d_in[2];
    const float* tr_m = (const float*)d_in[3];
    const float* W    = (const float*)d_in[4];
    // d_in[5] = b : cancels in diag_is - diag_em, unused.
    float* out = (float*)d_out;

    char* ws = (char*)d_ws;
    unsigned char* c8p = (unsigned char*)ws;                             // 8 MiB
    unsigned char* wtp = (unsigned char*)(ws + (size_t)8 * 1024 * 1024); // 1 MiB
    float*         delta = (float*)(ws + (size_t)9 * 1024 * 1024);       // 32 KiB

    prep_combo<<<4640, 256, 0, stream>>>(m, tr_m, c8p, W, wtp, delta);
    gemm_dot<<<1024, 256, 0, stream>>>(c8p, wtp, A_is, A_em, delta);
    hinge_sum<<<1, 256, 0, stream>>>(delta, out);
}